// Round 3
// baseline (273.146 us; speedup 1.0000x reference)
//
#include <hip/hip_runtime.h>
#include <hip/hip_bf16.h>
#include <stdint.h>

// KQV_28956669510232: out = softmax((x@Wq)(x@Wk)^T / 32, axis=keys) @ (x@Wv)
// B=4, S=2048, D=1024, fp32 in/out. bf16 MFMA GEMMs, materialized scores.
//
// R7: QKV split at the q,k / v boundary so every GEMM sits on its ideal grid:
//     - qk projection: 8-phase 256^2 (gemm8p, bias+bf16out), grid 8x32 = 256
//       blocks = exactly 1 round (the m201 design point; R5-verified path).
//     - v projection: m97 128^2 + fused vT-transpose epilogue (R6-verified
//       branch), grid 8x64, + XCD swizzle.
//     - PV: new 8-phase 128x256-tile variant (gemm8pv), grid 4x16x4 = 256
//       blocks, NT=32. B-side staging identical to verified template; A-side
//       halves on row-bit5 (1 load/half) aligned with quadrant-MH reads;
//       counted VMW(4) (6 loads/tile, 4 in flight for t+2).
//     - scores reads packed qk buffer (lda 2048).
// R6: fused prep; fused V-transpose epilogue. R5: 8-phase scores (kept).
//
// ws layout (~102 MB):
//   xb  bf16 [8192][1024]   @ 0         (16 MB)
//   wt  bf16 [3072][1024]   @ 16777216  (6 MB)   rows: q,k,v (W^T)
//   bc  f32  [3072]         @ 23068672
//   qk  bf16 [8192][2048]   @ 23080960  (32 MB)  cols: q(0-1023), k(1024-2047)
//   vT  bf16 [4][1024][2048]@ 56635392  (16 MB)
//   P   bf16 [4][2048][2048]@ 73412608  (32 MB)  scores -> P in place

typedef unsigned short u16;
typedef __bf16 bf16x8 __attribute__((ext_vector_type(8)));
typedef float  f32x4  __attribute__((ext_vector_type(4)));
typedef float  f32x16 __attribute__((ext_vector_type(16)));
typedef u16    u16x4  __attribute__((ext_vector_type(4)));
typedef u16    u16x8  __attribute__((ext_vector_type(8)));

__device__ __forceinline__ u16 f2bf(float f) {
  union { float f; uint32_t u; } v; v.f = f;
  uint32_t r = v.u + 0x7fffu + ((v.u >> 16) & 1u);   // RNE
  return (u16)(r >> 16);
}
__device__ __forceinline__ float bf2f(u16 b) {
  union { uint32_t u; float f; } v; v.u = (uint32_t)b << 16; return v.f;
}

#define GLD_LDS16(gp, lp) __builtin_amdgcn_global_load_lds(                   \
    (const __attribute__((address_space(1))) void*)(gp),                      \
    (__attribute__((address_space(3))) void*)(lp), 16, 0, 0)

// ---------------- fused prep: conv_x | W transpose+conv | bias concat -----

__global__ __launch_bounds__(256)
void prep_all(const float* __restrict__ x,
              const float* __restrict__ Wq, const float* __restrict__ Wk,
              const float* __restrict__ Wv,
              const float* __restrict__ bq, const float* __restrict__ bk,
              const float* __restrict__ bv,
              u16* __restrict__ xb, u16* __restrict__ wt,
              float* __restrict__ bc) {
  __shared__ float t[32][33];
  const int bid = blockIdx.x;
  if (bid < 4096) {
    int i = (bid * 256 + threadIdx.x) * 8;
    float4 v0 = *(const float4*)(x + i);
    float4 v1 = *(const float4*)(x + i + 4);
    u16x8 o;
    o[0] = f2bf(v0.x); o[1] = f2bf(v0.y); o[2] = f2bf(v0.z); o[3] = f2bf(v0.w);
    o[4] = f2bf(v1.x); o[5] = f2bf(v1.y); o[6] = f2bf(v1.z); o[7] = f2bf(v1.w);
    *(u16x8*)(xb + i) = o;
  } else if (bid < 4096 + 3072) {
    int b2 = bid - 4096;
    int z = b2 >> 10, rem = b2 & 1023;
    int e0 = (rem & 31) * 32, d0 = (rem >> 5) * 32;
    const float* W = z == 0 ? Wq : (z == 1 ? Wk : Wv);
    u16* dst = wt + (size_t)z * 1024 * 1024;
    int tx = threadIdx.x & 31, ty = threadIdx.x >> 5;
    #pragma unroll
    for (int i = 0; i < 4; ++i)
      t[ty + i * 8][tx] = W[(size_t)(d0 + ty + i * 8) * 1024 + e0 + tx];
    __syncthreads();
    #pragma unroll
    for (int i = 0; i < 4; ++i)
      dst[(size_t)(e0 + ty + i * 8) * 1024 + d0 + tx] =
          f2bf(t[tx][ty + i * 8]);
  } else {
    int i = (bid - 7168) * 256 + threadIdx.x;
    if (i < 3072)
      bc[i] = (i < 1024) ? bq[i] : (i < 2048 ? bk[i - 1024] : bv[i - 2048]);
  }
}

// ---------------- V projection (m97 128^2) with fused vT-transpose --------
// C = x @ Wv^T + bv, written as vT[b][e][s]. Grid (8, 64): bx = e-block,
// by = global s-block. XCD-swizzled (nwg = 512, %8 == 0).

__global__ __launch_bounds__(256)
void gemm_v(const u16* __restrict__ A, int lda,
            const u16* __restrict__ B, int ldb,
            const float* __restrict__ bias, int K,
            u16* __restrict__ vTp) {
  __shared__ __align__(16) u16 smem[128 * 132];   // 33792 B
  u16* As = smem;            // 128*64
  u16* Bs = smem + 8192;     // 128*64
  const int lane = threadIdx.x & 63;
  const int wv = threadIdx.x >> 6;

  const int flat = blockIdx.y * 8 + blockIdx.x;
  const int swz = (flat & 7) * 64 + (flat >> 3);
  const int bx = swz & 7, by = swz >> 3;

  const u16* Ab = A + (size_t)by * 128 * lda;
  const u16* Bb = B + (size_t)bx * 128 * ldb;

  const int srow = lane >> 3;
  const int scol = ((lane & 7) ^ (lane >> 3)) * 8;
  const int r32 = lane & 31;
  const int half = lane >> 5;
  const int rx = lane & 7;
  const int wm = (wv >> 1) * 64;
  const int wn = (wv & 1) * 64;

  f32x16 acc[2][2];
  #pragma unroll
  for (int i = 0; i < 2; ++i)
    #pragma unroll
    for (int j = 0; j < 2; ++j) acc[i][j] = (f32x16)0.0f;

  for (int k0 = 0; k0 < K; k0 += 64) {
    #pragma unroll
    for (int i = 0; i < 4; ++i) {
      int r = wv * 32 + i * 8;
      GLD_LDS16(Ab + (size_t)(r + srow) * lda + k0 + scol, As + r * 64);
      GLD_LDS16(Bb + (size_t)(r + srow) * ldb + k0 + scol, Bs + r * 64);
    }
    __syncthreads();

    bf16x8 af[2][4], bfr[2][4];
    #pragma unroll
    for (int i = 0; i < 2; ++i)
      #pragma unroll
      for (int t = 0; t < 4; ++t) {
        int pc = ((t * 2 + half) ^ rx) * 8;
        af[i][t]  = *(const bf16x8*)(As + (wm + i * 32 + r32) * 64 + pc);
        bfr[i][t] = *(const bf16x8*)(Bs + (wn + i * 32 + r32) * 64 + pc);
      }
    #pragma unroll
    for (int i = 0; i < 2; ++i)
      #pragma unroll
      for (int j = 0; j < 2; ++j)
        #pragma unroll
        for (int t = 0; t < 4; ++t)
          acc[i][j] = __builtin_amdgcn_mfma_f32_32x32x16_bf16(
              af[i][t], bfr[j][t], acc[i][j], 0, 0, 0);
    __syncthreads();
  }

  // transpose through LDS, write vT[b][e][s]
  u16 (*t)[132] = (u16(*)[132])smem;   // [n_local][m_local], pad 132
  #pragma unroll
  for (int i = 0; i < 2; ++i) {
    #pragma unroll
    for (int j = 0; j < 2; ++j) {
      const int nl = wn + j * 32 + r32;
      const float bvv = bias[bx * 128 + nl];
      #pragma unroll
      for (int eg = 0; eg < 4; ++eg) {
        const int mb = wm + i * 32 + 4 * half + 8 * eg;
        u16x4 o;
        #pragma unroll
        for (int q = 0; q < 4; ++q) o[q] = f2bf(acc[i][j][eg * 4 + q] + bvv);
        *(u16x4*)&t[nl][mb] = o;
      }
    }
  }
  __syncthreads();
  const int tid = threadIdx.x;
  const int bb = by >> 4;
  const int s0 = (by & 15) * 128 + (tid & 15) * 8;
  const int e_base = bx * 128;
  u16* dstb = vTp + (size_t)bb * 1024 * 2048;
  #pragma unroll
  for (int p = 0; p < 8; ++p) {
    const int el = (tid >> 4) + p * 16;
    u16x8 o;
    #pragma unroll
    for (int q = 0; q < 8; ++q) o[q] = t[el][(tid & 15) * 8 + q];
    *(u16x8*)(dstb + (size_t)(e_base + el) * 2048 + s0) = o;
  }
}

// ---------------- 8-phase 256x256 BT GEMM (qk projection + scores) --------
// C[m][n] = scale * sum_k A[m][k]*B[n][k] (+bias[n]); 512 threads = 8 waves
// (2M x 4N), wave tile 128x64, mfma 16x16x32, BK=64, 2-slot LDS dbuf,
// counted vmcnt(6) once per K-tile, setprio around MFMA, XOR-8 swizzle via
// pre-swizzled global source, bijective XCD swizzle. Race-free staging:
// every LDS overwrite issues >=1 barrier after the old data's last ds_read.

#define FENCE8 asm volatile("" ::: "memory")
#define BARR8  do { FENCE8; __builtin_amdgcn_s_barrier(); FENCE8; } while (0)
#define WAITL8 asm volatile("s_waitcnt lgkmcnt(0)" ::: "memory")
#define VMW(N) asm volatile("s_waitcnt vmcnt(" #N ")" ::: "memory")

#define STAGE_A8(S, H, TT) do {                                               \
    GLD_LDS16(pA[H][0] + (TT) * 64,                                           \
              As + (S) * 16384 + ((H) * 64 + wv * 8) * 64);                   \
    GLD_LDS16(pA[H][1] + (TT) * 64,                                           \
              As + (S) * 16384 + ((H) * 64 + 128 + wv * 8) * 64);             \
  } while (0)

#define STAGE_B8(S, H, TT) do {                                               \
    GLD_LDS16(pB[H][0] + (TT) * 64,                                           \
              Bs + (S) * 16384 + ((H) * 32 + (wv >> 2) * 64 + (wv & 3) * 8) * 64); \
    GLD_LDS16(pB[H][1] + (TT) * 64,                                           \
              Bs + (S) * 16384 + ((H) * 32 + 128 + (wv >> 2) * 64 + (wv & 3) * 8) * 64); \
  } while (0)

#define RD_A8(S, MH) do {                                                     \
    _Pragma("unroll")                                                         \
    for (int mf = 0; mf < 4; ++mf) {                                          \
      const u16* p_ = As + (S) * 16384 + rdA + ((MH) * 64 + mf * 16) * 64;    \
      a[mf][0] = *(const bf16x8*)(p_ + pos0);                                 \
      a[mf][1] = *(const bf16x8*)(p_ + pos1);                                 \
    }                                                                         \
  } while (0)

#define RD_B8(S, NH) do {                                                     \
    _Pragma("unroll")                                                         \
    for (int nf = 0; nf < 2; ++nf) {                                          \
      const u16* p_ = Bs + (S) * 16384 + rdB + ((NH) * 32 + nf * 16) * 64;    \
      b[nf][0] = *(const bf16x8*)(p_ + pos0);                                 \
      b[nf][1] = *(const bf16x8*)(p_ + pos1);                                 \
    }                                                                         \
  } while (0)

#define MFMA_Q8(MH, NH) do {                                                  \
    _Pragma("unroll")                                                         \
    for (int ks = 0; ks < 2; ++ks)                                            \
      _Pragma("unroll")                                                       \
      for (int mf = 0; mf < 4; ++mf)                                          \
        _Pragma("unroll")                                                     \
        for (int nf = 0; nf < 2; ++nf)                                        \
          acc[(MH) * 4 + mf][(NH) * 2 + nf] =                                 \
              __builtin_amdgcn_mfma_f32_16x16x32_bf16(                        \
                  a[mf][ks], b[nf][ks], acc[(MH) * 4 + mf][(NH) * 2 + nf],    \
                  0, 0, 0);                                                   \
  } while (0)

#define GROUP8(S, T, EN1, EN2, WAITST) do {                                   \
    RD_A8(S, 0); RD_B8(S, 0);                                                 \
    if (EN1) STAGE_B8((S) ^ 1, 0, (T) + 1);                                   \
    BARR8; WAITL8;                                                            \
    __builtin_amdgcn_s_setprio(1); MFMA_Q8(0, 0);                             \
    __builtin_amdgcn_s_setprio(0); BARR8;                                     \
    RD_B8(S, 1);                                                              \
    if (EN2) STAGE_A8(S, 0, (T) + 2);                                         \
    BARR8; WAITL8;                                                            \
    __builtin_amdgcn_s_setprio(1); MFMA_Q8(0, 1);                             \
    __builtin_amdgcn_s_setprio(0); BARR8;                                     \
    RD_A8(S, 1);                                                              \
    if (EN2) STAGE_B8(S, 1, (T) + 2);                                         \
    BARR8; WAITL8;                                                            \
    __builtin_amdgcn_s_setprio(1); MFMA_Q8(1, 1);                             \
    __builtin_amdgcn_s_setprio(0); BARR8;                                     \
    RD_B8(S, 0);                                                              \
    if (EN2) STAGE_A8(S, 1, (T) + 2);                                         \
    BARR8; WAITL8;                                                            \
    __builtin_amdgcn_s_setprio(1); MFMA_Q8(1, 0);                             \
    __builtin_amdgcn_s_setprio(0); WAITST; BARR8;                             \
  } while (0)

template <int NT, bool OUT_BF16, bool BIAS>
__global__ __launch_bounds__(512)
void gemm8p(const u16* __restrict__ A, int lda, long long sA,
            const u16* __restrict__ B, int ldb, long long sB,
            void* __restrict__ C, int ldc, long long sC,
            const float* __restrict__ bias, float scale) {
  __shared__ __align__(16) u16 As[2 * 256 * 64];
  __shared__ __align__(16) u16 Bs[2 * 256 * 64];

  const int lane = threadIdx.x & 63;
  const int wv   = threadIdx.x >> 6;    // 0..7
  const int wm   = wv >> 2;             // 0..1
  const int wn   = wv & 3;              // 0..3
  const int l15  = lane & 15;
  const int hi4  = lane >> 4;           // 0..3
  const int rx7  = lane & 7;
  const int srow = lane >> 3;           // 0..7
  const int scem = ((lane & 7) ^ srow) * 8;

  // bijective XCD swizzle (nwg % 8 == 0)
  const int nx = gridDim.x;
  const int flat = blockIdx.y * nx + blockIdx.x;
  const int nwg = nx * gridDim.y;
  const int cpx = nwg >> 3;
  const int swz = (flat & 7) * cpx + (flat >> 3);
  const int bx = swz % nx, by = swz / nx;

  const u16* Ab = A + (size_t)blockIdx.z * sA + (size_t)by * 256 * lda;
  const u16* Bb = B + (size_t)blockIdx.z * sB + (size_t)bx * 256 * ldb;

  const u16* pA[2][2];
  const u16* pB[2][2];
  #pragma unroll
  for (int h = 0; h < 2; ++h)
    #pragma unroll
    for (int r = 0; r < 2; ++r) {
      pA[h][r] = Ab + (size_t)(h * 64 + r * 128 + wv * 8 + srow) * lda + scem;
      pB[h][r] = Bb + (size_t)(h * 32 + r * 128 + (wv >> 2) * 64 +
                               (wv & 3) * 8 + srow) * ldb + scem;
    }

  const int rdA = (wm * 128 + l15) * 64;
  const int rdB = (wn * 64 + l15) * 64;
  const int pos0 = (hi4 ^ rx7) * 8;
  const int pos1 = ((4 + hi4) ^ rx7) * 8;

  f32x4 acc[8][4];
  #pragma unroll
  for (int i = 0; i < 8; ++i)
    #pragma unroll
    for (int j = 0; j < 4; ++j) acc[i][j] = (f32x4)0.0f;

  bf16x8 a[4][2], b[2][2];

  STAGE_A8(0, 0, 0); STAGE_B8(0, 1, 0); STAGE_A8(0, 1, 0); STAGE_B8(0, 0, 0);
  VMW(4);
  STAGE_A8(1, 0, 1); STAGE_B8(1, 1, 1); STAGE_A8(1, 1, 1);
  VMW(6);
  BARR8;

  #pragma unroll 1
  for (int i = 0; i < NT / 2 - 1; ++i) {
    const int t0 = 2 * i;
    GROUP8(0, t0,     1, 1, VMW(6));
    GROUP8(1, t0 + 1, 1, 1, VMW(6));
  }
  GROUP8(0, NT - 2, 1, 0, VMW(0));
  GROUP8(1, NT - 1, 0, 0, (void)0);

  const int m0 = by * 256 + wm * 128;
  const int n0 = bx * 256 + wn * 64;
  u16* Cb = (u16*)C + (size_t)blockIdx.z * sC;
  float* Cf = (float*)C + (size_t)blockIdx.z * sC;
  float bb[4];
  if (BIAS) {
    #pragma unroll
    for (int fn = 0; fn < 4; ++fn)
      bb[fn] = bias[n0 + (fn >> 1) * 32 + (fn & 1) * 16 + l15];
  }
  #pragma unroll
  for (int fm = 0; fm < 8; ++fm) {
    const int mb = m0 + (fm >> 2) * 64 + (fm & 3) * 16 + hi4 * 4;
    #pragma unroll
    for (int e = 0; e < 4; ++e) {
      const int m = mb + e;
      #pragma unroll
      for (int fn = 0; fn < 4; ++fn) {
        const int n = n0 + (fn >> 1) * 32 + (fn & 1) * 16 + l15;
        float v = acc[fm][fn][e] * scale;
        if (BIAS) v += bb[fn];
        if (OUT_BF16) Cb[(size_t)m * ldc + n] = f2bf(v);
        else          Cf[(size_t)m * ldc + n] = v;
      }
    }
  }
}

// ---------------- 8-phase 128x256 BT GEMM (PV) ----------------------------
// Same schedule; A-tile is 128 rows (halves on row-bit5, 1 load/half/thread,
// aligned with quadrant-MH reads: rows wm*64 + MH*32 + mf*16 + l15). B-side
// identical to the 256^2 template. 6 loads/K-tile; group-end VMW(4) leaves
// exactly the t+2 stages (A0+B1+A1 = 4 loads) in flight. f32 out.

#define STAGE_AV(S, H, TT) do {                                               \
    GLD_LDS16(pA[H] + (TT) * 64,                                              \
              As + (S) * 8192 + ((H) * 32 + (wv >> 2) * 64 + (wv & 3) * 8) * 64); \
  } while (0)

#define RD_AV(S, MH) do {                                                     \
    _Pragma("unroll")                                                         \
    for (int mf = 0; mf < 2; ++mf) {                                          \
      const u16* p_ = As + (S) * 8192 + rdA + ((MH) * 32 + mf * 16) * 64;     \
      a[mf][0] = *(const bf16x8*)(p_ + pos0);                                 \
      a[mf][1] = *(const bf16x8*)(p_ + pos1);                                 \
    }                                                                         \
  } while (0)

#define MFMA_QV(MH, NH) do {                                                  \
    _Pragma("unroll")                                                         \
    for (int ks = 0; ks < 2; ++ks)                                            \
      _Pragma("unroll")                                                       \
      for (int mf = 0; mf < 2; ++mf)                                          \
        _Pragma("unroll")                                                     \
        for (int nf = 0; nf < 2; ++nf)                                        \
          acc[(MH) * 2 + mf][(NH) * 2 + nf] =                                 \
              __builtin_amdgcn_mfma_f32_16x16x32_bf16(                        \
                  a[mf][ks], b[nf][ks], acc[(MH) * 2 + mf][(NH) * 2 + nf],    \
                  0, 0, 0);                                                   \
  } while (0)

#define GROUPV(S, T, EN1, EN2, WAITST) do {                                   \
    RD_AV(S, 0); RD_B8(S, 0);                                                 \
    if (EN1) STAGE_B8((S) ^ 1, 0, (T) + 1);                                   \
    BARR8; WAITL8;                                                            \
    __builtin_amdgcn_s_setprio(1); MFMA_QV(0, 0);                             \
    __builtin_amdgcn_s_setprio(0); BARR8;                                     \
    RD_B8(S, 1);                                                              \
    if (EN2) STAGE_AV(S, 0, (T) + 2);                                         \
    BARR8; WAITL8;                                                            \
    __builtin_amdgcn_s_setprio(1); MFMA_QV(0, 1);                             \
    __builtin_amdgcn_s_setprio(0); BARR8;                                     \
    RD_AV(S, 1);                                                              \
    if (EN2) STAGE_B8(S, 1, (T) + 2);                                         \
    BARR8; WAITL8;                                                            \
    __builtin_amdgcn_s_setprio(1); MFMA_QV(1, 1);                             \
    __builtin_amdgcn_s_setprio(0); BARR8;                                     \
    RD_B8(S, 0);                                                              \
    if (EN2) STAGE_AV(S, 1, (T) + 2);                                         \
    BARR8; WAITL8;                                                            \
    __builtin_amdgcn_s_setprio(1); MFMA_QV(1, 0);                             \
    __builtin_amdgcn_s_setprio(0); WAITST; BARR8;                             \
  } while (0)

template <int NT>
__global__ __launch_bounds__(512)
void gemm8pv(const u16* __restrict__ A, int lda, long long sA,
             const u16* __restrict__ B, int ldb, long long sB,
             float* __restrict__ C, int ldc, long long sC, float scale) {
  __shared__ __align__(16) u16 As[2 * 128 * 64];   // 32 KB
  __shared__ __align__(16) u16 Bs[2 * 256 * 64];   // 64 KB

  const int lane = threadIdx.x & 63;
  const int wv   = threadIdx.x >> 6;
  const int wm   = wv >> 2;
  const int wn   = wv & 3;
  const int l15  = lane & 15;
  const int hi4  = lane >> 4;
  const int rx7  = lane & 7;
  const int srow = lane >> 3;
  const int scem = ((lane & 7) ^ srow) * 8;

  // bijective XCD swizzle over the full 3D grid (4 x 16 x 4 = 256 blocks)
  const int flat = (blockIdx.z * gridDim.y + blockIdx.y) * gridDim.x + blockIdx.x;
  const int swz = (flat & 7) * 32 + (flat >> 3);
  const int bx = swz & 3, by = (swz >> 2) & 15, bz = swz >> 6;

  const u16* Ab = A + (size_t)bz * sA + (size_t)by * 128 * lda;
  const u16* Bb = B + (size_t)bz * sB + (size_t)bx * 256 * ldb;

  const u16* pA[2];
  const u16* pB[2][2];
  #pragma unroll
  for (int h = 0; h < 2; ++h) {
    pA[h] = Ab + (size_t)(h * 32 + (wv >> 2) * 64 + (wv & 3) * 8 + srow) * lda + scem;
    #pragma unroll
    for (int r = 0; r < 2; ++r)
      pB[h][r] = Bb + (size_t)(h * 32 + r * 128 + (wv >> 2) * 64 +
                               (wv & 3) * 8 + srow) * ldb + scem;
  }

  const int rdA = (wm * 64 + l15) * 64;
  const int rdB = (wn * 64 + l15) * 64;
  const int pos0 = (hi4 ^ rx7) * 8;
  const int pos1 = ((4 + hi4) ^ rx7) * 8;

  f32x4 acc[4][4];
  #pragma unroll
  for (int i = 0; i < 4; ++i)
    #pragma unroll
    for (int j = 0; j < 4; ++j) acc[i][j] = (f32x4)0.0f;

  bf16x8 a[2][2], b[2][2];

  // prologue: tile 0 complete (6 loads) + tile 1 A0,B1,A1 (4 loads)
  STAGE_AV(0, 0, 0); STAGE_B8(0, 1, 0); STAGE_AV(0, 1, 0); STAGE_B8(0, 0, 0);
  STAGE_AV(1, 0, 1); STAGE_B8(1, 1, 1); STAGE_AV(1, 1, 1);
  VMW(4);
  BARR8;

  #pragma unroll 1
  for (int i = 0; i < NT / 2 - 1; ++i) {
    const int t0 = 2 * i;
    GROUPV(0, t0,     1, 1, VMW(4));
    GROUPV(1, t0 + 1, 1, 1, VMW(4));
  }
  GROUPV(0, NT - 2, 1, 0, VMW(0));
  GROUPV(1, NT - 1, 0, 0, (void)0);

  // epilogue: m = by*128 + wm*64 + (am>>1)*32 + (am&1)*16 + hi4*4 + e
  //           n = bx*256 + wn*64 + (an>>1)*32 + (an&1)*16 + l15
  float* Cf = C + (size_t)bz * sC;
  const int m0 = by * 128 + wm * 64 + hi4 * 4;
  const int n0 = bx * 256 + wn * 64;
  #pragma unroll
  for (int am = 0; am < 4; ++am) {
    const int mb = m0 + (am >> 1) * 32 + (am & 1) * 16;
    #pragma unroll
    for (int e = 0; e < 4; ++e) {
      const int m = mb + e;
      #pragma unroll
      for (int an = 0; an < 4; ++an) {
        const int n = n0 + (an >> 1) * 32 + (an & 1) * 16 + l15;
        Cf[(size_t)m * ldc + n] = acc[am][an][e] * scale;
      }
    }
  }
}

// ---------------- softmax over bf16 rows of 2048, in place -------------

__global__ __launch_bounds__(256) void softmax_rows(u16* __restrict__ P) {
  __shared__ float red[4];
  const int t = threadIdx.x;
  const int lane = t & 63, wv = t >> 6;
  u16* row = P + (size_t)blockIdx.x * 2048;
  u16x8 w = ((const u16x8*)row)[t];
  float v[8];
  #pragma unroll
  for (int j = 0; j < 8; ++j) v[j] = bf2f(w[j]);
  float m = v[0];
  #pragma unroll
  for (int j = 1; j < 8; ++j) m = fmaxf(m, v[j]);
  #pragma unroll
  for (int off = 32; off > 0; off >>= 1) m = fmaxf(m, __shfl_down(m, off));
  if (lane == 0) red[wv] = m;
  __syncthreads();
  m = fmaxf(fmaxf(red[0], red[1]), fmaxf(red[2], red[3]));
  __syncthreads();
  float e[8], s = 0.f;
  #pragma unroll
  for (int j = 0; j < 8; ++j) { e[j] = exp2f((v[j] - m) * 1.44269504f); s += e[j]; }
  #pragma unroll
  for (int off = 32; off > 0; off >>= 1) s += __shfl_down(s, off);
  if (lane == 0) red[wv] = s;
  __syncthreads();
  s = red[0] + red[1] + red[2] + red[3];
  float inv = 1.0f / s;
  u16x8 o;
  #pragma unroll
  for (int j = 0; j < 8; ++j) o[j] = f2bf(e[j] * inv);
  ((u16x8*)row)[t] = o;
}

// ---------------- launch ----------------

extern "C" void kernel_launch(void* const* d_in, const int* in_sizes, int n_in,
                              void* d_out, int out_size, void* d_ws, size_t ws_size,
                              hipStream_t stream) {
  const float* x  = (const float*)d_in[0];
  const float* Wk = (const float*)d_in[1];
  const float* bk = (const float*)d_in[2];
  const float* Wq = (const float*)d_in[3];
  const float* bq = (const float*)d_in[4];
  const float* Wv = (const float*)d_in[5];
  const float* bv = (const float*)d_in[6];
  float* out = (float*)d_out;

  char* ws = (char*)d_ws;
  u16*   xb  = (u16*)(ws + 0);
  u16*   wt  = (u16*)(ws + 16777216);
  float* bc  = (float*)(ws + 23068672);
  u16*   qk  = (u16*)(ws + 23080960);
  u16*   vT  = (u16*)(ws + 56635392);
  u16*   P   = (u16*)(ws + 73412608);
  (void)in_sizes; (void)n_in; (void)out_size; (void)ws_size;

  // 1. fused prep: x->bf16 (4096 blk) | W^T->bf16 (3072 blk) | bias (12 blk)
  prep_all<<<7180, 256, 0, stream>>>(x, Wq, Wk, Wv, bq, bk, bv, xb, wt, bc);

  // 2a. qk projection: [8192,1024] x [2048,1024]^T (+bias) -> qk bf16;
  //     8-phase 256^2, grid 8x32 = 256 blocks = exactly 1 round
  gemm8p<16, true, true><<<dim3(8, 32, 1), 512, 0, stream>>>(
      xb, 1024, 0LL, wt, 1024, 0LL, (void*)qk, 2048, 0LL, bc, 1.0f);

  // 2b. v projection + fused transpose -> vT  (m97 128^2, grid 8x64)
  gemm_v<<<dim3(8, 64, 1), 256, 0, stream>>>(
      xb, 1024, wt + 2048 * 1024, 1024, bc + 2048, 1024, vT);

  // 3. scores = q @ k^T / 32 -> bf16 P (8-phase 256^2; 8x8x4 = 1 round)
  gemm8p<16, true, false><<<dim3(8, 8, 4), 512, 0, stream>>>(
      qk, 2048, 2048LL * 2048, qk + 1024, 2048, 2048LL * 2048,
      (void*)P, 2048, 2048LL * 2048, nullptr, 0.03125f);

  // 4. row softmax on bf16 P, in place
  softmax_rows<<<8192, 256, 0, stream>>>(P);

  // 5. out = P @ V  (8-phase 128x256, grid 4x16x4 = 256 blocks = 1 round)
  gemm8pv<32><<<dim3(4, 16, 4), 512, 0, stream>>>(
      P, 2048, 2048LL * 2048, vT, 2048, 1024LL * 2048,
      out, 1024, 2048LL * 1024, 1.0f);
}

// Round 4
// 257.614 us; speedup vs baseline: 1.0603x; 1.0603x over previous
//
#include <hip/hip_runtime.h>
#include <hip/hip_bf16.h>
#include <stdint.h>

// KQV_28956669510232: out = softmax((x@Wq)(x@Wk)^T / 32, axis=keys) @ (x@Wv)
// B=4, S=2048, D=1024, fp32 in/out. bf16 MFMA GEMMs, materialized scores.
//
// R8: PV reverted to the R4/R6-verified gemm_bt8 (m97-style, 512 blocks =
//     2/CU). R7's 128x256 8-phase PV regressed (59.8us, 575 TF): half the
//     MFMA per phase (8 vs 16) with full per-phase barrier cost + NT=32
//     doubled phase count. Regime gate = 1-round grid AND >=16 MFMA/phase.
//     Kept from R7: qk/v split (qk 8-phase 256^2 at exactly 256 blocks;
//     v-projection m97 128^2 with fused vT-transpose epilogue), scores on
//     packed qk (lda 2048), fused prep.
//
// ws layout (~102 MB):
//   xb  bf16 [8192][1024]   @ 0         (16 MB)
//   wt  bf16 [3072][1024]   @ 16777216  (6 MB)   rows: q,k,v (W^T)
//   bc  f32  [3072]         @ 23068672
//   qk  bf16 [8192][2048]   @ 23080960  (32 MB)  cols: q(0-1023), k(1024-2047)
//   vT  bf16 [4][1024][2048]@ 56635392  (16 MB)
//   P   bf16 [4][2048][2048]@ 73412608  (32 MB)  scores -> P in place

typedef unsigned short u16;
typedef __bf16 bf16x8 __attribute__((ext_vector_type(8)));
typedef float  f32x4  __attribute__((ext_vector_type(4)));
typedef float  f32x16 __attribute__((ext_vector_type(16)));
typedef u16    u16x4  __attribute__((ext_vector_type(4)));
typedef u16    u16x8  __attribute__((ext_vector_type(8)));

__device__ __forceinline__ u16 f2bf(float f) {
  union { float f; uint32_t u; } v; v.f = f;
  uint32_t r = v.u + 0x7fffu + ((v.u >> 16) & 1u);   // RNE
  return (u16)(r >> 16);
}
__device__ __forceinline__ float bf2f(u16 b) {
  union { uint32_t u; float f; } v; v.u = (uint32_t)b << 16; return v.f;
}

#define GLD_LDS16(gp, lp) __builtin_amdgcn_global_load_lds(                   \
    (const __attribute__((address_space(1))) void*)(gp),                      \
    (__attribute__((address_space(3))) void*)(lp), 16, 0, 0)

// ---------------- fused prep: conv_x | W transpose+conv | bias concat -----

__global__ __launch_bounds__(256)
void prep_all(const float* __restrict__ x,
              const float* __restrict__ Wq, const float* __restrict__ Wk,
              const float* __restrict__ Wv,
              const float* __restrict__ bq, const float* __restrict__ bk,
              const float* __restrict__ bv,
              u16* __restrict__ xb, u16* __restrict__ wt,
              float* __restrict__ bc) {
  __shared__ float t[32][33];
  const int bid = blockIdx.x;
  if (bid < 4096) {
    int i = (bid * 256 + threadIdx.x) * 8;
    float4 v0 = *(const float4*)(x + i);
    float4 v1 = *(const float4*)(x + i + 4);
    u16x8 o;
    o[0] = f2bf(v0.x); o[1] = f2bf(v0.y); o[2] = f2bf(v0.z); o[3] = f2bf(v0.w);
    o[4] = f2bf(v1.x); o[5] = f2bf(v1.y); o[6] = f2bf(v1.z); o[7] = f2bf(v1.w);
    *(u16x8*)(xb + i) = o;
  } else if (bid < 4096 + 3072) {
    int b2 = bid - 4096;
    int z = b2 >> 10, rem = b2 & 1023;
    int e0 = (rem & 31) * 32, d0 = (rem >> 5) * 32;
    const float* W = z == 0 ? Wq : (z == 1 ? Wk : Wv);
    u16* dst = wt + (size_t)z * 1024 * 1024;
    int tx = threadIdx.x & 31, ty = threadIdx.x >> 5;
    #pragma unroll
    for (int i = 0; i < 4; ++i)
      t[ty + i * 8][tx] = W[(size_t)(d0 + ty + i * 8) * 1024 + e0 + tx];
    __syncthreads();
    #pragma unroll
    for (int i = 0; i < 4; ++i)
      dst[(size_t)(e0 + ty + i * 8) * 1024 + d0 + tx] =
          f2bf(t[tx][ty + i * 8]);
  } else {
    int i = (bid - 7168) * 256 + threadIdx.x;
    if (i < 3072)
      bc[i] = (i < 1024) ? bq[i] : (i < 2048 ? bk[i - 1024] : bv[i - 2048]);
  }
}

// ---------------- V projection (m97 128^2) with fused vT-transpose --------
// C = x @ Wv^T + bv, written as vT[b][e][s]. Grid (8, 64): bx = e-block,
// by = global s-block. XCD-swizzled (nwg = 512, %8 == 0).

__global__ __launch_bounds__(256)
void gemm_v(const u16* __restrict__ A, int lda,
            const u16* __restrict__ B, int ldb,
            const float* __restrict__ bias, int K,
            u16* __restrict__ vTp) {
  __shared__ __align__(16) u16 smem[128 * 132];   // 33792 B
  u16* As = smem;            // 128*64
  u16* Bs = smem + 8192;     // 128*64
  const int lane = threadIdx.x & 63;
  const int wv = threadIdx.x >> 6;

  const int flat = blockIdx.y * 8 + blockIdx.x;
  const int swz = (flat & 7) * 64 + (flat >> 3);
  const int bx = swz & 7, by = swz >> 3;

  const u16* Ab = A + (size_t)by * 128 * lda;
  const u16* Bb = B + (size_t)bx * 128 * ldb;

  const int srow = lane >> 3;
  const int scol = ((lane & 7) ^ (lane >> 3)) * 8;
  const int r32 = lane & 31;
  const int half = lane >> 5;
  const int rx = lane & 7;
  const int wm = (wv >> 1) * 64;
  const int wn = (wv & 1) * 64;

  f32x16 acc[2][2];
  #pragma unroll
  for (int i = 0; i < 2; ++i)
    #pragma unroll
    for (int j = 0; j < 2; ++j) acc[i][j] = (f32x16)0.0f;

  for (int k0 = 0; k0 < K; k0 += 64) {
    #pragma unroll
    for (int i = 0; i < 4; ++i) {
      int r = wv * 32 + i * 8;
      GLD_LDS16(Ab + (size_t)(r + srow) * lda + k0 + scol, As + r * 64);
      GLD_LDS16(Bb + (size_t)(r + srow) * ldb + k0 + scol, Bs + r * 64);
    }
    __syncthreads();

    bf16x8 af[2][4], bfr[2][4];
    #pragma unroll
    for (int i = 0; i < 2; ++i)
      #pragma unroll
      for (int t = 0; t < 4; ++t) {
        int pc = ((t * 2 + half) ^ rx) * 8;
        af[i][t]  = *(const bf16x8*)(As + (wm + i * 32 + r32) * 64 + pc);
        bfr[i][t] = *(const bf16x8*)(Bs + (wn + i * 32 + r32) * 64 + pc);
      }
    #pragma unroll
    for (int i = 0; i < 2; ++i)
      #pragma unroll
      for (int j = 0; j < 2; ++j)
        #pragma unroll
        for (int t = 0; t < 4; ++t)
          acc[i][j] = __builtin_amdgcn_mfma_f32_32x32x16_bf16(
              af[i][t], bfr[j][t], acc[i][j], 0, 0, 0);
    __syncthreads();
  }

  // transpose through LDS, write vT[b][e][s]
  u16 (*t)[132] = (u16(*)[132])smem;   // [n_local][m_local], pad 132
  #pragma unroll
  for (int i = 0; i < 2; ++i) {
    #pragma unroll
    for (int j = 0; j < 2; ++j) {
      const int nl = wn + j * 32 + r32;
      const float bvv = bias[bx * 128 + nl];
      #pragma unroll
      for (int eg = 0; eg < 4; ++eg) {
        const int mb = wm + i * 32 + 4 * half + 8 * eg;
        u16x4 o;
        #pragma unroll
        for (int q = 0; q < 4; ++q) o[q] = f2bf(acc[i][j][eg * 4 + q] + bvv);
        *(u16x4*)&t[nl][mb] = o;
      }
    }
  }
  __syncthreads();
  const int tid = threadIdx.x;
  const int bb = by >> 4;
  const int s0 = (by & 15) * 128 + (tid & 15) * 8;
  const int e_base = bx * 128;
  u16* dstb = vTp + (size_t)bb * 1024 * 2048;
  #pragma unroll
  for (int p = 0; p < 8; ++p) {
    const int el = (tid >> 4) + p * 16;
    u16x8 o;
    #pragma unroll
    for (int q = 0; q < 8; ++q) o[q] = t[el][(tid & 15) * 8 + q];
    *(u16x8*)(dstb + (size_t)(e_base + el) * 2048 + s0) = o;
  }
}

// ---------------- 8-phase 256x256 BT GEMM (qk projection + scores) --------
// C[m][n] = scale * sum_k A[m][k]*B[n][k] (+bias[n]); 512 threads = 8 waves
// (2M x 4N), wave tile 128x64, mfma 16x16x32, BK=64, 2-slot LDS dbuf,
// counted vmcnt(6) once per K-tile, setprio around MFMA, XOR-8 swizzle via
// pre-swizzled global source, bijective XCD swizzle. Race-free staging:
// every LDS overwrite issues >=1 barrier after the old data's last ds_read.

#define FENCE8 asm volatile("" ::: "memory")
#define BARR8  do { FENCE8; __builtin_amdgcn_s_barrier(); FENCE8; } while (0)
#define WAITL8 asm volatile("s_waitcnt lgkmcnt(0)" ::: "memory")
#define VMW(N) asm volatile("s_waitcnt vmcnt(" #N ")" ::: "memory")

#define STAGE_A8(S, H, TT) do {                                               \
    GLD_LDS16(pA[H][0] + (TT) * 64,                                           \
              As + (S) * 16384 + ((H) * 64 + wv * 8) * 64);                   \
    GLD_LDS16(pA[H][1] + (TT) * 64,                                           \
              As + (S) * 16384 + ((H) * 64 + 128 + wv * 8) * 64);             \
  } while (0)

#define STAGE_B8(S, H, TT) do {                                               \
    GLD_LDS16(pB[H][0] + (TT) * 64,                                           \
              Bs + (S) * 16384 + ((H) * 32 + (wv >> 2) * 64 + (wv & 3) * 8) * 64); \
    GLD_LDS16(pB[H][1] + (TT) * 64,                                           \
              Bs + (S) * 16384 + ((H) * 32 + 128 + (wv >> 2) * 64 + (wv & 3) * 8) * 64); \
  } while (0)

#define RD_A8(S, MH) do {                                                     \
    _Pragma("unroll")                                                         \
    for (int mf = 0; mf < 4; ++mf) {                                          \
      const u16* p_ = As + (S) * 16384 + rdA + ((MH) * 64 + mf * 16) * 64;    \
      a[mf][0] = *(const bf16x8*)(p_ + pos0);                                 \
      a[mf][1] = *(const bf16x8*)(p_ + pos1);                                 \
    }                                                                         \
  } while (0)

#define RD_B8(S, NH) do {                                                     \
    _Pragma("unroll")                                                         \
    for (int nf = 0; nf < 2; ++nf) {                                          \
      const u16* p_ = Bs + (S) * 16384 + rdB + ((NH) * 32 + nf * 16) * 64;    \
      b[nf][0] = *(const bf16x8*)(p_ + pos0);                                 \
      b[nf][1] = *(const bf16x8*)(p_ + pos1);                                 \
    }                                                                         \
  } while (0)

#define MFMA_Q8(MH, NH) do {                                                  \
    _Pragma("unroll")                                                         \
    for (int ks = 0; ks < 2; ++ks)                                            \
      _Pragma("unroll")                                                       \
      for (int mf = 0; mf < 4; ++mf)                                          \
        _Pragma("unroll")                                                     \
        for (int nf = 0; nf < 2; ++nf)                                        \
          acc[(MH) * 4 + mf][(NH) * 2 + nf] =                                 \
              __builtin_amdgcn_mfma_f32_16x16x32_bf16(                        \
                  a[mf][ks], b[nf][ks], acc[(MH) * 4 + mf][(NH) * 2 + nf],    \
                  0, 0, 0);                                                   \
  } while (0)

#define GROUP8(S, T, EN1, EN2, WAITST) do {                                   \
    RD_A8(S, 0); RD_B8(S, 0);                                                 \
    if (EN1) STAGE_B8((S) ^ 1, 0, (T) + 1);                                   \
    BARR8; WAITL8;                                                            \
    __builtin_amdgcn_s_setprio(1); MFMA_Q8(0, 0);                             \
    __builtin_amdgcn_s_setprio(0); BARR8;                                     \
    RD_B8(S, 1);                                                              \
    if (EN2) STAGE_A8(S, 0, (T) + 2);                                         \
    BARR8; WAITL8;                                                            \
    __builtin_amdgcn_s_setprio(1); MFMA_Q8(0, 1);                             \
    __builtin_amdgcn_s_setprio(0); BARR8;                                     \
    RD_A8(S, 1);                                                              \
    if (EN2) STAGE_B8(S, 1, (T) + 2);                                         \
    BARR8; WAITL8;                                                            \
    __builtin_amdgcn_s_setprio(1); MFMA_Q8(1, 1);                             \
    __builtin_amdgcn_s_setprio(0); BARR8;                                     \
    RD_B8(S, 0);                                                              \
    if (EN2) STAGE_A8(S, 1, (T) + 2);                                         \
    BARR8; WAITL8;                                                            \
    __builtin_amdgcn_s_setprio(1); MFMA_Q8(1, 0);                             \
    __builtin_amdgcn_s_setprio(0); WAITST; BARR8;                             \
  } while (0)

template <int NT, bool OUT_BF16, bool BIAS>
__global__ __launch_bounds__(512)
void gemm8p(const u16* __restrict__ A, int lda, long long sA,
            const u16* __restrict__ B, int ldb, long long sB,
            void* __restrict__ C, int ldc, long long sC,
            const float* __restrict__ bias, float scale) {
  __shared__ __align__(16) u16 As[2 * 256 * 64];
  __shared__ __align__(16) u16 Bs[2 * 256 * 64];

  const int lane = threadIdx.x & 63;
  const int wv   = threadIdx.x >> 6;    // 0..7
  const int wm   = wv >> 2;             // 0..1
  const int wn   = wv & 3;              // 0..3
  const int l15  = lane & 15;
  const int hi4  = lane >> 4;           // 0..3
  const int rx7  = lane & 7;
  const int srow = lane >> 3;           // 0..7
  const int scem = ((lane & 7) ^ srow) * 8;

  // bijective XCD swizzle (nwg % 8 == 0)
  const int nx = gridDim.x;
  const int flat = blockIdx.y * nx + blockIdx.x;
  const int nwg = nx * gridDim.y;
  const int cpx = nwg >> 3;
  const int swz = (flat & 7) * cpx + (flat >> 3);
  const int bx = swz % nx, by = swz / nx;

  const u16* Ab = A + (size_t)blockIdx.z * sA + (size_t)by * 256 * lda;
  const u16* Bb = B + (size_t)blockIdx.z * sB + (size_t)bx * 256 * ldb;

  const u16* pA[2][2];
  const u16* pB[2][2];
  #pragma unroll
  for (int h = 0; h < 2; ++h)
    #pragma unroll
    for (int r = 0; r < 2; ++r) {
      pA[h][r] = Ab + (size_t)(h * 64 + r * 128 + wv * 8 + srow) * lda + scem;
      pB[h][r] = Bb + (size_t)(h * 32 + r * 128 + (wv >> 2) * 64 +
                               (wv & 3) * 8 + srow) * ldb + scem;
    }

  const int rdA = (wm * 128 + l15) * 64;
  const int rdB = (wn * 64 + l15) * 64;
  const int pos0 = (hi4 ^ rx7) * 8;
  const int pos1 = ((4 + hi4) ^ rx7) * 8;

  f32x4 acc[8][4];
  #pragma unroll
  for (int i = 0; i < 8; ++i)
    #pragma unroll
    for (int j = 0; j < 4; ++j) acc[i][j] = (f32x4)0.0f;

  bf16x8 a[4][2], b[2][2];

  STAGE_A8(0, 0, 0); STAGE_B8(0, 1, 0); STAGE_A8(0, 1, 0); STAGE_B8(0, 0, 0);
  VMW(4);
  STAGE_A8(1, 0, 1); STAGE_B8(1, 1, 1); STAGE_A8(1, 1, 1);
  VMW(6);
  BARR8;

  #pragma unroll 1
  for (int i = 0; i < NT / 2 - 1; ++i) {
    const int t0 = 2 * i;
    GROUP8(0, t0,     1, 1, VMW(6));
    GROUP8(1, t0 + 1, 1, 1, VMW(6));
  }
  GROUP8(0, NT - 2, 1, 0, VMW(0));
  GROUP8(1, NT - 1, 0, 0, (void)0);

  const int m0 = by * 256 + wm * 128;
  const int n0 = bx * 256 + wn * 64;
  u16* Cb = (u16*)C + (size_t)blockIdx.z * sC;
  float* Cf = (float*)C + (size_t)blockIdx.z * sC;
  float bb[4];
  if (BIAS) {
    #pragma unroll
    for (int fn = 0; fn < 4; ++fn)
      bb[fn] = bias[n0 + (fn >> 1) * 32 + (fn & 1) * 16 + l15];
  }
  #pragma unroll
  for (int fm = 0; fm < 8; ++fm) {
    const int mb = m0 + (fm >> 2) * 64 + (fm & 3) * 16 + hi4 * 4;
    #pragma unroll
    for (int e = 0; e < 4; ++e) {
      const int m = mb + e;
      #pragma unroll
      for (int fn = 0; fn < 4; ++fn) {
        const int n = n0 + (fn >> 1) * 32 + (fn & 1) * 16 + l15;
        float v = acc[fm][fn][e] * scale;
        if (BIAS) v += bb[fn];
        if (OUT_BF16) Cb[(size_t)m * ldc + n] = f2bf(v);
        else          Cf[(size_t)m * ldc + n] = v;
      }
    }
  }
}

// ---------------- PV GEMM: 512-thread m97-style (8 waves, 2m x 4n) --------
// R4/R6-verified. Grid (8,16,4) = 512 blocks = 2/CU = 16 waves/CU.

__global__ __launch_bounds__(512)
void gemm_bt8(const u16* __restrict__ A, int lda, long long sA,
              const u16* __restrict__ B, int ldb, long long sB,
              float* __restrict__ C, int ldc, long long sC,
              int K, float scale) {
  __shared__ u16 As[128 * 64];
  __shared__ u16 Bs[128 * 64];
  const int lane = threadIdx.x & 63;
  const int wv = threadIdx.x >> 6;          // 0..7

  const u16* Ab = A + (size_t)blockIdx.z * sA + (size_t)blockIdx.y * 128 * lda;
  const u16* Bb = B + (size_t)blockIdx.z * sB + (size_t)blockIdx.x * 128 * ldb;

  const int srow = lane >> 3;
  const int scol = ((lane & 7) ^ (lane >> 3)) * 8;
  const int r32 = lane & 31;
  const int half = lane >> 5;
  const int rx = lane & 7;
  const int wm = (wv >> 2) * 64;
  const int wn = (wv & 3) * 32;

  f32x16 acc[2];
  acc[0] = (f32x16)0.0f; acc[1] = (f32x16)0.0f;

  for (int k0 = 0; k0 < K; k0 += 64) {
    #pragma unroll
    for (int i = 0; i < 2; ++i) {
      int r = wv * 16 + i * 8;
      GLD_LDS16(Ab + (size_t)(r + srow) * lda + k0 + scol, As + r * 64);
      GLD_LDS16(Bb + (size_t)(r + srow) * ldb + k0 + scol, Bs + r * 64);
    }
    __syncthreads();

    bf16x8 af[2][4], bfr[4];
    #pragma unroll
    for (int t = 0; t < 4; ++t) {
      int pc = ((t * 2 + half) ^ rx) * 8;
      af[0][t] = *(const bf16x8*)(As + (wm + r32) * 64 + pc);
      af[1][t] = *(const bf16x8*)(As + (wm + 32 + r32) * 64 + pc);
      bfr[t]   = *(const bf16x8*)(Bs + (wn + r32) * 64 + pc);
    }
    #pragma unroll
    for (int i = 0; i < 2; ++i)
      #pragma unroll
      for (int t = 0; t < 4; ++t)
        acc[i] = __builtin_amdgcn_mfma_f32_32x32x16_bf16(
            af[i][t], bfr[t], acc[i], 0, 0, 0);
    __syncthreads();
  }

  const int ccol = blockIdx.x * 128 + wn + r32;
  const int crow0 = blockIdx.y * 128 + wm + 4 * half;
  float* Cf = C + (size_t)blockIdx.z * sC;
  #pragma unroll
  for (int i = 0; i < 2; ++i)
    #pragma unroll
    for (int e = 0; e < 16; ++e) {
      int m = crow0 + i * 32 + (e & 3) + 8 * (e >> 2);
      Cf[(size_t)m * ldc + ccol] = acc[i][e] * scale;
    }
}

// ---------------- softmax over bf16 rows of 2048, in place -------------

__global__ __launch_bounds__(256) void softmax_rows(u16* __restrict__ P) {
  __shared__ float red[4];
  const int t = threadIdx.x;
  const int lane = t & 63, wv = t >> 6;
  u16* row = P + (size_t)blockIdx.x * 2048;
  u16x8 w = ((const u16x8*)row)[t];
  float v[8];
  #pragma unroll
  for (int j = 0; j < 8; ++j) v[j] = bf2f(w[j]);
  float m = v[0];
  #pragma unroll
  for (int j = 1; j < 8; ++j) m = fmaxf(m, v[j]);
  #pragma unroll
  for (int off = 32; off > 0; off >>= 1) m = fmaxf(m, __shfl_down(m, off));
  if (lane == 0) red[wv] = m;
  __syncthreads();
  m = fmaxf(fmaxf(red[0], red[1]), fmaxf(red[2], red[3]));
  __syncthreads();
  float e[8], s = 0.f;
  #pragma unroll
  for (int j = 0; j < 8; ++j) { e[j] = exp2f((v[j] - m) * 1.44269504f); s += e[j]; }
  #pragma unroll
  for (int off = 32; off > 0; off >>= 1) s += __shfl_down(s, off);
  if (lane == 0) red[wv] = s;
  __syncthreads();
  s = red[0] + red[1] + red[2] + red[3];
  float inv = 1.0f / s;
  u16x8 o;
  #pragma unroll
  for (int j = 0; j < 8; ++j) o[j] = f2bf(e[j] * inv);
  ((u16x8*)row)[t] = o;
}

// ---------------- launch ----------------

extern "C" void kernel_launch(void* const* d_in, const int* in_sizes, int n_in,
                              void* d_out, int out_size, void* d_ws, size_t ws_size,
                              hipStream_t stream) {
  const float* x  = (const float*)d_in[0];
  const float* Wk = (const float*)d_in[1];
  const float* bk = (const float*)d_in[2];
  const float* Wq = (const float*)d_in[3];
  const float* bq = (const float*)d_in[4];
  const float* Wv = (const float*)d_in[5];
  const float* bv = (const float*)d_in[6];
  float* out = (float*)d_out;

  char* ws = (char*)d_ws;
  u16*   xb  = (u16*)(ws + 0);
  u16*   wt  = (u16*)(ws + 16777216);
  float* bc  = (float*)(ws + 23068672);
  u16*   qk  = (u16*)(ws + 23080960);
  u16*   vT  = (u16*)(ws + 56635392);
  u16*   P   = (u16*)(ws + 73412608);
  (void)in_sizes; (void)n_in; (void)out_size; (void)ws_size;

  // 1. fused prep: x->bf16 (4096 blk) | W^T->bf16 (3072 blk) | bias (12 blk)
  prep_all<<<7180, 256, 0, stream>>>(x, Wq, Wk, Wv, bq, bk, bv, xb, wt, bc);

  // 2a. qk projection: [8192,1024] x [2048,1024]^T (+bias) -> qk bf16;
  //     8-phase 256^2, grid 8x32 = 256 blocks = exactly 1 round
  gemm8p<16, true, true><<<dim3(8, 32, 1), 512, 0, stream>>>(
      xb, 1024, 0LL, wt, 1024, 0LL, (void*)qk, 2048, 0LL, bc, 1.0f);

  // 2b. v projection + fused transpose -> vT  (m97 128^2, grid 8x64)
  gemm_v<<<dim3(8, 64, 1), 256, 0, stream>>>(
      xb, 1024, wt + 2048 * 1024, 1024, bc + 2048, 1024, vT);

  // 3. scores = q @ k^T / 32 -> bf16 P (8-phase 256^2; 8x8x4 = 1 round)
  gemm8p<16, true, false><<<dim3(8, 8, 4), 512, 0, stream>>>(
      qk, 2048, 2048LL * 2048, qk + 1024, 2048, 2048LL * 2048,
      (void*)P, 2048, 2048LL * 2048, nullptr, 0.03125f);

  // 4. row softmax on bf16 P, in place
  softmax_rows<<<8192, 256, 0, stream>>>(P);

  // 5. out = P @ V  (R4/R6-verified m97-style 512-thread, 512 blocks)
  gemm_bt8<<<dim3(8, 16, 4), 512, 0, stream>>>(
      P, 2048, 2048LL * 2048, vT, 2048, 1024LL * 2048,
      out, 1024, 2048LL * 1024, 2048, 1.0f);
}